// Round 1
// baseline (82.131 us; speedup 1.0000x reference)
//
#include <hip/hip_runtime.h>
#include <hip/hip_bf16.h>
#include <stdint.h>

typedef __bf16 bf16_t;
typedef float  f32x4  __attribute__((ext_vector_type(4)));
typedef short  s16x8  __attribute__((ext_vector_type(8)));
typedef bf16_t bf16x8 __attribute__((ext_vector_type(8)));
typedef int    i32x4  __attribute__((ext_vector_type(4)));

static constexpr int M_ = 64;
static constexpr int K_ = 4096;
static constexpr int N_ = 14336;
static constexpr int KP8 = K_ / 8;   // 512 int32 per row of B_packed
// GS=128 -> 32 scale groups; one group = 4 K-steps of 32

// ---------------- x fp32 -> bf16 (row-major [64][4096]) ----------------
__global__ void xconv_kernel(const float* __restrict__ x, i32x4* __restrict__ xb) {
    int t = blockIdx.x * blockDim.x + threadIdx.x;      // 32768 threads, 8 elems each
    const float4* p = reinterpret_cast<const float4*>(x) + 2 * t;
    float4 a = p[0], b = p[1];
    union { bf16x8 h; i32x4 v; } z;
    z.h[0] = (bf16_t)a.x; z.h[1] = (bf16_t)a.y; z.h[2] = (bf16_t)a.z; z.h[3] = (bf16_t)a.w;
    z.h[4] = (bf16_t)b.x; z.h[5] = (bf16_t)b.y; z.h[6] = (bf16_t)b.z; z.h[7] = (bf16_t)b.w;
    xb[t] = z.v;
}

// ---------------- main fused dequant + GEMM ----------------
// grid = 448 blocks (BN=32), block = 512 threads = 8 waves.
// wave w: wn = w&1 (16-col sub-tile), wk = w>>1 (K-chunk of 1024).
// Each wave: 4 MFMA m-tiles (M=64) x 1 n-tile x 32 K-steps, no barriers in loop.
// K-split partials reduced via LDS, single coalesced-ish store (deterministic).
template<bool PRE>
__global__ __launch_bounds__(512)
void gemm_kernel(const float* __restrict__ xf, const ushort* __restrict__ xb,
                 const int* __restrict__ bpk, const float* __restrict__ s,
                 float* __restrict__ out)
{
    __shared__ f32x4 red[8][4][64];                     // 32 KB, conflict-free layout
    const int lane = threadIdx.x & 63;
    const int w    = threadIdx.x >> 6;
    const int wn   = w & 1;
    const int wk   = w >> 1;                            // 0..3
    const int h    = lane >> 4;                         // quarter-wave id 0..3
    const int l16  = lane & 15;
    const int ncol = blockIdx.x * 32 + wn * 16 + l16;   // this lane's output column

    const int* __restrict__ brow = bpk + (size_t)ncol * KP8;

    f32x4 acc[4] = {f32x4{0,0,0,0}, f32x4{0,0,0,0}, f32x4{0,0,0,0}, f32x4{0,0,0,0}};

    // K chunk [wk*1024, wk*1024+1024) = 8 scale-groups of 128
    for (int g = 0; g < 8; ++g) {
        const int gg = wk * 8 + g;                      // global group id 0..31
        const float sc  = s[gg * N_ + ncol];
        const float msc = -8.0f * sc;
        // the 4 packed dwords this lane needs for the group's 4 K-steps
        uint32_t us[4];
        us[0] = (uint32_t)brow[gg * 16 +  0 + h];
        us[1] = (uint32_t)brow[gg * 16 +  4 + h];
        us[2] = (uint32_t)brow[gg * 16 +  8 + h];
        us[3] = (uint32_t)brow[gg * 16 + 12 + h];
        #pragma unroll
        for (int t = 0; t < 4; ++t) {
            const uint32_t u = us[t];
            const int k0 = gg * 128 + t * 32;           // K-step base
            // dequant 8 nibbles -> bf16x8 B-fragment.
            // frag slot j (k = k0 + h*8 + j): j=2p -> nibble p, j=2p+1 -> nibble p+4
            union { bf16x8 h8; s16x8 v; } bw;
            #pragma unroll
            for (int p = 0; p < 4; ++p) {
                uint32_t vlo = (u >> (4 * p)) & 0xFu;
                uint32_t vhi = (u >> (16 + 4 * p)) & 0xFu;
                bw.h8[2 * p]     = (bf16_t)fmaf((float)vlo, sc, msc);
                bw.h8[2 * p + 1] = (bf16_t)fmaf((float)vhi, sc, msc);
            }
            #pragma unroll
            for (int mt = 0; mt < 4; ++mt) {
                const int row = mt * 16 + l16;
                s16x8 a;
                if constexpr (PRE) {
                    a = *reinterpret_cast<const s16x8*>(xb + (size_t)row * K_ + k0 + h * 8);
                } else {
                    const float* xp = xf + (size_t)row * K_ + k0 + h * 8;
                    float4 f0 = *reinterpret_cast<const float4*>(xp);
                    float4 f1 = *reinterpret_cast<const float4*>(xp + 4);
                    union { bf16x8 h8; s16x8 v; } ua;
                    ua.h8[0] = (bf16_t)f0.x; ua.h8[1] = (bf16_t)f0.y;
                    ua.h8[2] = (bf16_t)f0.z; ua.h8[3] = (bf16_t)f0.w;
                    ua.h8[4] = (bf16_t)f1.x; ua.h8[5] = (bf16_t)f1.y;
                    ua.h8[6] = (bf16_t)f1.z; ua.h8[7] = (bf16_t)f1.w;
                    a = ua.v;
                }
                acc[mt] = __builtin_amdgcn_mfma_f32_16x16x32_bf16(a, bw.v, acc[mt], 0, 0, 0);
            }
        }
    }

    // ---- reduce the 4 K-split partials via LDS ----
    #pragma unroll
    for (int mt = 0; mt < 4; ++mt) red[w][mt][lane] = acc[mt];
    __syncthreads();

    if (wk == 0) {
        #pragma unroll
        for (int mt = 0; mt < 4; ++mt) {
            f32x4 v = red[wn][mt][lane];
            v += red[2 + wn][mt][lane];
            v += red[4 + wn][mt][lane];
            v += red[6 + wn][mt][lane];
            const int rbase = mt * 16 + h * 4;          // C/D: row=(lane>>4)*4+q, col=lane&15
            #pragma unroll
            for (int q = 0; q < 4; ++q)
                out[(size_t)(rbase + q) * N_ + ncol] = v[q];
        }
    }
}

extern "C" void kernel_launch(void* const* d_in, const int* in_sizes, int n_in,
                              void* d_out, int out_size, void* d_ws, size_t ws_size,
                              hipStream_t stream) {
    const float* x   = (const float*)d_in[0];
    const int*   bpk = (const int*)d_in[1];
    const float* s   = (const float*)d_in[2];
    float*       out = (float*)d_out;

    if (ws_size >= (size_t)(M_ * K_ * 2)) {
        xconv_kernel<<<128, 256, 0, stream>>>(x, (i32x4*)d_ws);
        gemm_kernel<true><<<448, 512, 0, stream>>>(x, (const ushort*)d_ws, bpk, s, out);
    } else {
        gemm_kernel<false><<<448, 512, 0, stream>>>(x, nullptr, bpk, s, out);
    }
}

// Round 3
// 43.624 us; speedup vs baseline: 1.8827x; 1.8827x over previous
//
#include <hip/hip_runtime.h>
#include <hip/hip_bf16.h>
#include <stdint.h>

typedef __bf16 bf16_t;
typedef float  f32x4  __attribute__((ext_vector_type(4)));
typedef short  s16x8  __attribute__((ext_vector_type(8)));
typedef bf16_t bf16x8 __attribute__((ext_vector_type(8)));
typedef int    i32x4  __attribute__((ext_vector_type(4)));

static constexpr int M_  = 64;
static constexpr int K_  = 4096;
static constexpr int N_  = 14336;
static constexpr int KP8 = K_ / 8;   // 512 packed dwords per B row

// ---------------- x fp32 -> bf16 (row-major [64][4096]) ----------------
__global__ void xconv_kernel(const float* __restrict__ x, i32x4* __restrict__ xb) {
    int t = blockIdx.x * blockDim.x + threadIdx.x;      // 32768 threads, 8 elems each
    const float4* p = reinterpret_cast<const float4*>(x) + 2 * t;
    float4 a = p[0], b = p[1];
    union { bf16x8 h; i32x4 v; } z;
    z.h[0] = (bf16_t)a.x; z.h[1] = (bf16_t)a.y; z.h[2] = (bf16_t)a.z; z.h[3] = (bf16_t)a.w;
    z.h[4] = (bf16_t)b.x; z.h[5] = (bf16_t)b.y; z.h[6] = (bf16_t)b.z; z.h[7] = (bf16_t)b.w;
    xb[t] = z.v;
}

__device__ __forceinline__ void gload_lds16(const void* g, void* l) {
    __builtin_amdgcn_global_load_lds(
        (const __attribute__((address_space(1))) void*)g,
        (__attribute__((address_space(3))) void*)l, 16, 0, 0);
}

// ---------------- main fused dequant + GEMM ----------------
// grid = 448 (BN=32), block = 512 = 8 waves. Wave w owns K-chunk [w*512,(w+1)*512).
// B tile (32 cols x 512 dwords = 64KB) staged in LDS via global_load_lds_dwordx4,
// XOR-swizzled so inner ds_read_b32 is 2-lanes/bank (free). Each wave computes
// 2 n-subtiles x 4 m-subtiles; 8 K-partials reduced via LDS (aliased over B buf).
template<bool PRE>
__global__ __launch_bounds__(512, 4)
void gemm_kernel(const float* __restrict__ xf, const ushort* __restrict__ xb,
                 const int* __restrict__ bpk, const float* __restrict__ s,
                 float* __restrict__ out)
{
    __shared__ __align__(16) uint32_t lbs[16384];       // 64 KB
    const int lane = threadIdx.x & 63;
    const int w    = threadIdx.x >> 6;                  // wave id = K-chunk id, 0..7
    const int h    = lane >> 4;                         // 0..3
    const int l16  = lane & 15;
    const int n0   = blockIdx.x * 32;

    // ---- stage B tile: instr i covers LDS dwords [i*256, i*256+256) ----
    // LDS[col][d'] = packed[n0+col][d' ^ swz(col)], swz = (col&12) | ((col&1)<<4)
    #pragma unroll
    for (int q = 0; q < 8; ++q) {
        const int i    = w * 8 + q;
        const int col  = i >> 1;
        const int swz  = (col & 12) | ((col & 1) << 4);
        const int dp   = (i & 1) * 256 + 4 * lane;       // d' base (multiple of 4)
        const int dsrc = dp ^ swz;                       // global dword idx, 16B-aligned
        gload_lds16(bpk + (size_t)(n0 + col) * KP8 + dsrc, &lbs[i * 256]);
    }

    // ---- prefetch the 8 scales this wave needs (hidden under staging) ----
    float scv[4][2];
    #pragma unroll
    for (int g = 0; g < 4; ++g)
        #pragma unroll
        for (int nt = 0; nt < 2; ++nt)
            scv[g][nt] = s[(size_t)(w * 4 + g) * N_ + n0 + nt * 16 + l16];

    __syncthreads();                                    // staging complete

    f32x4 acc[2][4];
    #pragma unroll
    for (int nt = 0; nt < 2; ++nt)
        #pragma unroll
        for (int mt = 0; mt < 4; ++mt) acc[nt][mt] = f32x4{0, 0, 0, 0};

    // swz(col) depends only on l16 (bit4 of col cancels): same for nt=0/1
    const int swzr = (l16 & 12) | ((l16 & 1) << 4);

    #pragma unroll
    for (int g = 0; g < 4; ++g) {
        const int gg = w * 4 + g;                       // scale-group id 0..31
        // B packed dwords for this group: [nt][t], via swizzled LDS
        uint32_t us[2][4];
        #pragma unroll
        for (int nt = 0; nt < 2; ++nt)
            #pragma unroll
            for (int t = 0; t < 4; ++t) {
                const int d = gg * 16 + t * 4 + h;
                us[nt][t] = lbs[(nt * 16 + l16) * 512 + (d ^ swzr)];
            }
        const float sc0 = scv[g][0], msc0 = -8.0f * sc0;
        const float sc1 = scv[g][1], msc1 = -8.0f * sc1;

        #pragma unroll
        for (int t = 0; t < 4; ++t) {
            const int k0 = gg * 128 + t * 32;
            // A fragments for all 4 m-subtiles of this K-step
            s16x8 a[4];
            #pragma unroll
            for (int mt = 0; mt < 4; ++mt) {
                const int row = mt * 16 + l16;
                if constexpr (PRE) {
                    a[mt] = *reinterpret_cast<const s16x8*>(xb + (size_t)row * K_ + k0 + h * 8);
                } else {
                    const float* xp = xf + (size_t)row * K_ + k0 + h * 8;
                    float4 f0 = *reinterpret_cast<const float4*>(xp);
                    float4 f1 = *reinterpret_cast<const float4*>(xp + 4);
                    union { bf16x8 h8; s16x8 v; } ua;
                    ua.h8[0] = (bf16_t)f0.x; ua.h8[1] = (bf16_t)f0.y;
                    ua.h8[2] = (bf16_t)f0.z; ua.h8[3] = (bf16_t)f0.w;
                    ua.h8[4] = (bf16_t)f1.x; ua.h8[5] = (bf16_t)f1.y;
                    ua.h8[6] = (bf16_t)f1.z; ua.h8[7] = (bf16_t)f1.w;
                    a[mt] = ua.v;
                }
            }
            #pragma unroll
            for (int nt = 0; nt < 2; ++nt) {
                const uint32_t u  = us[nt][t];
                const float sc  = nt ? sc1 : sc0;
                const float msc = nt ? msc1 : msc0;
                // frag slot j (k = k0 + h*8 + j): j=2p -> nibble p, j=2p+1 -> nibble p+4
                union { bf16x8 h8; s16x8 v; } bw;
                #pragma unroll
                for (int p = 0; p < 4; ++p) {
                    uint32_t vlo = (u >> (4 * p)) & 0xFu;
                    uint32_t vhi = (u >> (16 + 4 * p)) & 0xFu;
                    bw.h8[2 * p]     = (bf16_t)fmaf((float)vlo, sc, msc);
                    bw.h8[2 * p + 1] = (bf16_t)fmaf((float)vhi, sc, msc);
                }
                #pragma unroll
                for (int mt = 0; mt < 4; ++mt)
                    acc[nt][mt] = __builtin_amdgcn_mfma_f32_16x16x32_bf16(a[mt], bw.v, acc[nt][mt], 0, 0, 0);
            }
        }
    }

    // ---- reduce 8 K-partials via LDS (alias over B buffer) ----
    __syncthreads();                                    // all B reads done
    f32x4* red = reinterpret_cast<f32x4*>(lbs);         // [w][slot][lane]
    #pragma unroll
    for (int nt = 0; nt < 2; ++nt)
        #pragma unroll
        for (int mt = 0; mt < 4; ++mt)
            red[(w * 8 + nt * 4 + mt) * 64 + lane] = acc[nt][mt];
    __syncthreads();

    // thread (w, lane) owns output slot s = w: nt = w>>2, mt = w&3
    f32x4 v = red[w * 64 + lane];
    #pragma unroll
    for (int w2 = 1; w2 < 8; ++w2) v += red[(w2 * 8 + w) * 64 + lane];
    const int nt = w >> 2, mt = w & 3;
    const int rbase = mt * 16 + h * 4;                  // C/D: row=(lane>>4)*4+q, col=lane&15
    const int col   = n0 + nt * 16 + l16;
    #pragma unroll
    for (int q = 0; q < 4; ++q)
        out[(size_t)(rbase + q) * N_ + col] = v[q];
}

extern "C" void kernel_launch(void* const* d_in, const int* in_sizes, int n_in,
                              void* d_out, int out_size, void* d_ws, size_t ws_size,
                              hipStream_t stream) {
    const float* x   = (const float*)d_in[0];
    const int*   bpk = (const int*)d_in[1];
    const float* s   = (const float*)d_in[2];
    float*       out = (float*)d_out;

    if (ws_size >= (size_t)(M_ * K_ * 2)) {
        xconv_kernel<<<128, 256, 0, stream>>>(x, (i32x4*)d_ws);
        gemm_kernel<true><<<448, 512, 0, stream>>>(x, (const ushort*)d_ws, bpk, s, out);
    } else {
        gemm_kernel<false><<<448, 512, 0, stream>>>(x, nullptr, bpk, s, out);
    }
}